// Round 5
// baseline (260.778 us; speedup 1.0000x reference)
//
#include <hip/hip_runtime.h>
#include <stdint.h>

// GroupedLinear: y[b, g*256+o] = sum_i x[b, g*256+i] * W[g,o,i] + bias[g,o]
// B=8192, G=16, GIN=GOUT=256. fp32 in/out, bf16 MFMA compute.
//
// ~276 MB compulsory HBM -> ~44 us floor @ 6.3 TB/s.
// v3 (90us) pipelined loads across barriers but LOADS(k+2) shared regs with
// WRITE(k+1), forcing issue AFTER the vmcnt stall -> per-phase HBM issue gap
// (~50% HBM duty cycle: 13.5Kcy phases vs 6.4Kcy of HBM-cold bytes).
// v5: ping-pong prefetch register sets R0/R1; phase =
//   barrier -> LOADS(k+2)->R[k&1] -> COMPUTE(buf) -> WRITE(k+1<-R[~k&1])
// so tile k+2 is always in the memory queue before the wave stalls on k+1.
// Raw s_barrier + lgkmcnt(0)-only drain (global loads NEVER drained).

#define IN_F   4096
#define OUT_F  4096
#define GIN    256
#define GOUT   256

#define BM 128
#define BN 128
#define BK 64
#define KTOT 256

using short8  = __attribute__((ext_vector_type(8))) short;
using floatx4 = __attribute__((ext_vector_type(4))) float;

// round-to-nearest-even fp32 -> bf16 (branch-free)
__device__ __forceinline__ short f2bf_rne(float f) {
    unsigned u = __builtin_bit_cast(unsigned, f);
    unsigned r = u + 0x7FFFu + ((u >> 16) & 1u);
    return (short)(r >> 16);
}

__device__ __forceinline__ short8 pack8(floatx4 f0, floatx4 f1) {
    short8 p;
    p[0] = f2bf_rne(f0[0]); p[1] = f2bf_rne(f0[1]);
    p[2] = f2bf_rne(f0[2]); p[3] = f2bf_rne(f0[3]);
    p[4] = f2bf_rne(f1[0]); p[5] = f2bf_rne(f1[1]);
    p[6] = f2bf_rne(f1[2]); p[7] = f2bf_rne(f1[3]);
    return p;
}

// writer-side sync: drain own ds_writes (lgkm only), raw barrier.
// sched_barrier(0) per guide rule #18.
#define SYNC_PHASE() do {                                        \
    asm volatile("s_waitcnt lgkmcnt(0)" ::: "memory");           \
    __builtin_amdgcn_sched_barrier(0);                           \
    __builtin_amdgcn_s_barrier();                                \
    __builtin_amdgcn_sched_barrier(0);                           \
} while (0)

__global__ __launch_bounds__(256, 2)
void grouped_linear_kernel(const float* __restrict__ X,
                           const float* __restrict__ W,
                           const float* __restrict__ Bias,
                           float* __restrict__ Out) {
    // bf16 LDS tiles, XOR-swizzled in 8-elem (16B) chunks: chunk q of row r
    // at q ^ (r&7) -> <=2-way bank aliasing (free) for ds_write_b128 and
    // fragment ds_read_b128. Double-buffered: 64 KB total -> 2 blocks/CU.
    __shared__ __align__(16) short lsA[2][BM * BK];   // 2 x 16 KB
    __shared__ __align__(16) short lsB[2][BN * BK];   // 2 x 16 KB

    const int t    = threadIdx.x;
    const int lane = t & 63;
    const int wave = t >> 6;
    const int wm   = wave >> 1;     // wave row (0..1) -> 64 rows
    const int wn   = wave & 1;      // wave col (0..1) -> 64 cols
    const int lrow = lane & 15;
    const int quad = lane >> 4;     // 0..3

    const int bn   = blockIdx.x & 31;   // 32 col-tiles of 128
    const int bm   = blockIdx.x >> 5;   // 64 row-tiles of 128
    const int g    = bn >> 1;           // group (2 col-tiles per group)
    const int row0 = bm * BM;
    const int col0 = bn * BN;
    const int nlb  = (bn & 1) * BN;     // N offset inside this group's W

    const float* Wg = W + (size_t)g * GOUT * GIN + (size_t)nlb * GIN;
    const float* Xg = X + (size_t)row0 * IN_F + g * GIN;

    floatx4 acc[4][4];
    #pragma unroll
    for (int i = 0; i < 4; ++i)
        #pragma unroll
        for (int j = 0; j < 4; ++j)
            acc[i][j] = (floatx4){0.f, 0.f, 0.f, 0.f};

    // staging geometry: thread covers rows r0+32i, 8 consecutive floats at c8.
    // 8 threads span one 64-float K-slice -> fully coalesced 32B/lane.
    const int c8 = (t & 7) * 8;
    const int q0 = (t & 7);
    const int r0 = (t >> 3);

    // two ping-pong prefetch register sets (static names, rule #20)
    floatx4 raA[4][2], rbA[4][2];   // set A
    floatx4 raB[4][2], rbB[4][2];   // set B

    // ---- issue 16 global_load_dwordx4 for K-tile kt into a reg set ----
    auto LOADS = [&](int kt, floatx4 (&ra)[4][2], floatx4 (&rb)[4][2]) {
        const int kbase = kt * BK;
        #pragma unroll
        for (int i = 0; i < 4; ++i) {
            const float* src = Xg + (size_t)(r0 + 32 * i) * IN_F + kbase + c8;
            ra[i][0] = *(const floatx4*)src;
            ra[i][1] = *(const floatx4*)(src + 4);
        }
        #pragma unroll
        for (int i = 0; i < 4; ++i) {
            const float* src = Wg + (size_t)(r0 + 32 * i) * GIN + kbase + c8;
            rb[i][0] = *(const floatx4*)src;
            rb[i][1] = *(const floatx4*)(src + 4);
        }
    };

    // ---- cvt a reg set -> bf16, swizzled ds_write into buffer `buf` ----
    auto WRITE = [&](int buf, floatx4 (&ra)[4][2], floatx4 (&rb)[4][2]) {
        #pragma unroll
        for (int i = 0; i < 4; ++i) {
            int r = r0 + 32 * i;
            int q = q0 ^ (r & 7);
            *(short8*)&lsA[buf][r * BK + q * 8] = pack8(ra[i][0], ra[i][1]);
        }
        #pragma unroll
        for (int i = 0; i < 4; ++i) {
            int n = r0 + 32 * i;
            int q = q0 ^ (n & 7);
            *(short8*)&lsB[buf][n * BK + q * 8] = pack8(rb[i][0], rb[i][1]);
        }
    };

    // ---- 32 MFMA from buffer `buf` ----
    auto COMPUTE = [&](int buf) {
        #pragma unroll
        for (int kk = 0; kk < 2; ++kk) {
            int kb = kk * 32 + quad * 8;
            int qs = kb >> 3;
            short8 a[4], b[4];
            #pragma unroll
            for (int i = 0; i < 4; ++i) {
                int r = wm * 64 + i * 16 + lrow;
                a[i] = *(const short8*)&lsA[buf][r * BK + ((qs ^ (r & 7)) * 8)];
            }
            #pragma unroll
            for (int j = 0; j < 4; ++j) {
                int n = wn * 64 + j * 16 + lrow;
                b[j] = *(const short8*)&lsB[buf][n * BK + ((qs ^ (n & 7)) * 8)];
            }
            #pragma unroll
            for (int i = 0; i < 4; ++i)
                #pragma unroll
                for (int j = 0; j < 4; ++j)
                    acc[i][j] = __builtin_amdgcn_mfma_f32_16x16x32_bf16(
                        a[i], b[j], acc[i][j], 0, 0, 0);
        }
    };

    // Pipeline, KTOT/BK = 4 tiles, reg sets: tile0->A, 1->B, 2->A, 3->B.
    // Hazard audit (LDS): WRITE(buf0,kt2) in ph1 -- all COMPUTE(buf0,kt0)
    // finished before the ph0/ph1 barrier. WRITE(buf1,kt3) in ph2 -- all
    // COMPUTE(buf1,kt1) before ph1/ph2 barrier. Reg sets: LOADS(kt2)->A in
    // ph0 only after WRITE(kt0<-A) in prologue (program order, same thread).
    // Global loads are never vmcnt-drained at barriers; each WRITE's cvt
    // waits only on its own (long-issued) reg set while the next tile's
    // 64KB/block is already streaming.
    LOADS(0, raA, rbA);
    LOADS(1, raB, rbB);
    WRITE(0, raA, rbA);             // stalls on tile0 only; tile1 in flight
    SYNC_PHASE();                   // buf0 ready
    LOADS(2, raA, rbA);             // issue BEFORE any stall
    COMPUTE(0);                     // kt0
    WRITE(1, raB, rbB);             // stall on kt1 (covered); kt2 streaming
    SYNC_PHASE();                   // buf1 ready
    LOADS(3, raB, rbB);
    COMPUTE(1);                     // kt1
    WRITE(0, raA, rbA);             // kt2
    SYNC_PHASE();                   // buf0 ready
    COMPUTE(0);                     // kt2
    WRITE(1, raB, rbB);             // kt3
    SYNC_PHASE();                   // buf1 ready
    COMPUTE(1);                     // kt3

    // ---- epilogue: C/D layout col=lane&15, row=quad*4+reg; add bias ----
    #pragma unroll
    for (int j = 0; j < 4; ++j) {
        int gc = col0 + wn * 64 + j * 16 + lrow;
        float bias = Bias[gc];
        #pragma unroll
        for (int i = 0; i < 4; ++i) {
            int gr = row0 + wm * 64 + i * 16 + quad * 4;
            floatx4 v = acc[i][j];
            #pragma unroll
            for (int rg = 0; rg < 4; ++rg)
                Out[(size_t)(gr + rg) * OUT_F + gc] = v[rg] + bias;
        }
    }
}

extern "C" void kernel_launch(void* const* d_in, const int* in_sizes, int n_in,
                              void* d_out, int out_size, void* d_ws, size_t ws_size,
                              hipStream_t stream) {
    const float* X    = (const float*)d_in[0];   // [8192, 4096]
    const float* W    = (const float*)d_in[1];   // [16, 256, 256]
    const float* Bias = (const float*)d_in[2];   // [16, 256]
    float*       Out  = (float*)d_out;           // [8192, 4096]

    dim3 grid(64 * 32);   // 64 M-tiles x 32 N-tiles
    dim3 block(256);
    grouped_linear_kernel<<<grid, block, 0, stream>>>(X, W, Bias, Out);
}

// Round 8
// 256.848 us; speedup vs baseline: 1.0153x; 1.0153x over previous
//
#include <hip/hip_runtime.h>
#include <stdint.h>

// GroupedLinear: y[b, g*256+o] = sum_i x[b, g*256+i] * W[g,o,i] + bias[g,o]
// B=8192, G=16, GIN=GOUT=256. fp32 in/out, bf16 MFMA compute.
//
// ~285 MB HBM traffic -> ~45 us floor @ 6.3 TB/s.
// v3 (90us): loads pipelined across raw barriers, but LOADS shared regs with
// WRITE -> issue gap during WRITE's vmcnt stall (~50% HBM duty).
// v5 (107us, FAILED): ping-pong reg sets, but compiler capped VGPR at 128
// (heuristic targets 4 waves/EU; LDS caps us at 2 blocks/CU anyway) ->
// spills (+14MB WRITE_SIZE) and/or loads sunk to uses. Design untested.
// v6: same ping-pong, ENFORCED: amdgpu_waves_per_eu(2,2) grants the 256-VGPR
// budget; sched_barrier(0) pins LOADS before COMPUTE and COMPUTE before
// WRITE's vmcnt stall. Phase: loads(k+2) stream | MFMA(k) | stall on k+1
// (covered by k+2 in flight) | ds_write(k+1) | lgkm-only barrier.

#define IN_F   4096
#define OUT_F  4096
#define GIN    256
#define GOUT   256

#define BM 128
#define BN 128
#define BK 64
#define KTOT 256

using short8  = __attribute__((ext_vector_type(8))) short;
using floatx4 = __attribute__((ext_vector_type(4))) float;

// round-to-nearest-even fp32 -> bf16 (branch-free)
__device__ __forceinline__ short f2bf_rne(float f) {
    unsigned u = __builtin_bit_cast(unsigned, f);
    unsigned r = u + 0x7FFFu + ((u >> 16) & 1u);
    return (short)(r >> 16);
}

__device__ __forceinline__ short8 pack8(floatx4 f0, floatx4 f1) {
    short8 p;
    p[0] = f2bf_rne(f0[0]); p[1] = f2bf_rne(f0[1]);
    p[2] = f2bf_rne(f0[2]); p[3] = f2bf_rne(f0[3]);
    p[4] = f2bf_rne(f1[0]); p[5] = f2bf_rne(f1[1]);
    p[6] = f2bf_rne(f1[2]); p[7] = f2bf_rne(f1[3]);
    return p;
}

#define PIN() __builtin_amdgcn_sched_barrier(0)

// writer-side sync: drain own ds_writes (lgkm only -- global loads stay in
// flight), raw barrier. sched_barrier(0) per guide rule #18.
#define SYNC_PHASE() do {                                        \
    asm volatile("s_waitcnt lgkmcnt(0)" ::: "memory");           \
    __builtin_amdgcn_sched_barrier(0);                           \
    __builtin_amdgcn_s_barrier();                                \
    __builtin_amdgcn_sched_barrier(0);                           \
} while (0)

__global__ __launch_bounds__(256) __attribute__((amdgpu_waves_per_eu(2, 2)))
void grouped_linear_kernel(const float* __restrict__ X,
                           const float* __restrict__ W,
                           const float* __restrict__ Bias,
                           float* __restrict__ Out) {
    // bf16 LDS tiles, XOR-swizzled in 8-elem (16B) chunks: chunk q of row r
    // at q ^ (r&7) -> <=2-way bank aliasing (free) for ds_write_b128 and
    // fragment ds_read_b128. Double-buffered: 64 KB total -> 2 blocks/CU.
    __shared__ __align__(16) short lsA[2][BM * BK];   // 2 x 16 KB
    __shared__ __align__(16) short lsB[2][BN * BK];   // 2 x 16 KB

    const int t    = threadIdx.x;
    const int lane = t & 63;
    const int wave = t >> 6;
    const int wm   = wave >> 1;     // wave row (0..1) -> 64 rows
    const int wn   = wave & 1;      // wave col (0..1) -> 64 cols
    const int lrow = lane & 15;
    const int quad = lane >> 4;     // 0..3

    const int bn   = blockIdx.x & 31;   // 32 col-tiles of 128
    const int bm   = blockIdx.x >> 5;   // 64 row-tiles of 128
    const int g    = bn >> 1;           // group (2 col-tiles per group)
    const int row0 = bm * BM;
    const int col0 = bn * BN;
    const int nlb  = (bn & 1) * BN;     // N offset inside this group's W

    const float* Wg = W + (size_t)g * GOUT * GIN + (size_t)nlb * GIN;
    const float* Xg = X + (size_t)row0 * IN_F + g * GIN;

    floatx4 acc[4][4];
    #pragma unroll
    for (int i = 0; i < 4; ++i)
        #pragma unroll
        for (int j = 0; j < 4; ++j)
            acc[i][j] = (floatx4){0.f, 0.f, 0.f, 0.f};

    // staging geometry: thread covers rows r0+32i, 8 consecutive floats at c8.
    // 8 threads span one 64-float K-slice -> fully coalesced 32B/lane.
    const int c8 = (t & 7) * 8;
    const int q0 = (t & 7);
    const int r0 = (t >> 3);

    // two ping-pong prefetch register sets (static names, rule #20)
    floatx4 raA[4][2], rbA[4][2];   // set A
    floatx4 raB[4][2], rbB[4][2];   // set B

    // ---- issue 16 global_load_dwordx4 for K-tile kt into a reg set ----
    auto LOADS = [&](int kt, floatx4 (&ra)[4][2], floatx4 (&rb)[4][2]) {
        const int kbase = kt * BK;
        #pragma unroll
        for (int i = 0; i < 4; ++i) {
            const float* src = Xg + (size_t)(r0 + 32 * i) * IN_F + kbase + c8;
            ra[i][0] = *(const floatx4*)src;
            ra[i][1] = *(const floatx4*)(src + 4);
        }
        #pragma unroll
        for (int i = 0; i < 4; ++i) {
            const float* src = Wg + (size_t)(r0 + 32 * i) * GIN + kbase + c8;
            rb[i][0] = *(const floatx4*)src;
            rb[i][1] = *(const floatx4*)(src + 4);
        }
    };

    // ---- cvt a reg set -> bf16, swizzled ds_write into buffer `buf` ----
    auto WRITE = [&](int buf, floatx4 (&ra)[4][2], floatx4 (&rb)[4][2]) {
        #pragma unroll
        for (int i = 0; i < 4; ++i) {
            int r = r0 + 32 * i;
            int q = q0 ^ (r & 7);
            *(short8*)&lsA[buf][r * BK + q * 8] = pack8(ra[i][0], ra[i][1]);
        }
        #pragma unroll
        for (int i = 0; i < 4; ++i) {
            int n = r0 + 32 * i;
            int q = q0 ^ (n & 7);
            *(short8*)&lsB[buf][n * BK + q * 8] = pack8(rb[i][0], rb[i][1]);
        }
    };

    // ---- 32 MFMA from buffer `buf` ----
    auto COMPUTE = [&](int buf) {
        #pragma unroll
        for (int kk = 0; kk < 2; ++kk) {
            int kb = kk * 32 + quad * 8;
            int qs = kb >> 3;
            short8 a[4], b[4];
            #pragma unroll
            for (int i = 0; i < 4; ++i) {
                int r = wm * 64 + i * 16 + lrow;
                a[i] = *(const short8*)&lsA[buf][r * BK + ((qs ^ (r & 7)) * 8)];
            }
            #pragma unroll
            for (int j = 0; j < 4; ++j) {
                int n = wn * 64 + j * 16 + lrow;
                b[j] = *(const short8*)&lsB[buf][n * BK + ((qs ^ (n & 7)) * 8)];
            }
            #pragma unroll
            for (int i = 0; i < 4; ++i)
                #pragma unroll
                for (int j = 0; j < 4; ++j)
                    acc[i][j] = __builtin_amdgcn_mfma_f32_16x16x32_bf16(
                        a[i], b[j], acc[i][j], 0, 0, 0);
        }
    };

    // Pipeline, KTOT/BK = 4 tiles, reg sets: tile0->A, 1->B, 2->A, 3->B.
    // LDS hazards: WRITE(buf0,kt2) only after the barrier following all
    // COMPUTE(buf0,kt0); WRITE(buf1,kt3) after barrier following
    // COMPUTE(buf1,kt1). Reg hazards: LOADS(kt2)->A after WRITE(kt0<-A)
    // in program order. Global loads never vmcnt-drained at barriers.
    // PIN() enforces: loads issue first, MFMAs before the vmcnt stall.
    LOADS(0, raA, rbA);
    LOADS(1, raB, rbB);
    WRITE(0, raA, rbA);             // stalls on tile0 only; tile1 in flight
    SYNC_PHASE();                   // buf0 ready
    LOADS(2, raA, rbA);             // issue BEFORE any stall
    PIN();
    COMPUTE(0);                     // kt0
    PIN();
    WRITE(1, raB, rbB);             // stall on kt1 (covered); kt2 streaming
    SYNC_PHASE();                   // buf1 ready
    LOADS(3, raB, rbB);
    PIN();
    COMPUTE(1);                     // kt1
    PIN();
    WRITE(0, raA, rbA);             // kt2
    SYNC_PHASE();                   // buf0 ready
    COMPUTE(0);                     // kt2
    PIN();
    WRITE(1, raB, rbB);             // kt3
    SYNC_PHASE();                   // buf1 ready
    COMPUTE(1);                     // kt3

    // ---- epilogue: C/D layout col=lane&15, row=quad*4+reg; add bias ----
    #pragma unroll
    for (int j = 0; j < 4; ++j) {
        int gc = col0 + wn * 64 + j * 16 + lrow;
        float bias = Bias[gc];
        #pragma unroll
        for (int i = 0; i < 4; ++i) {
            int gr = row0 + wm * 64 + i * 16 + quad * 4;
            floatx4 v = acc[i][j];
            #pragma unroll
            for (int rg = 0; rg < 4; ++rg)
                Out[(size_t)(gr + rg) * OUT_F + gc] = v[rg] + bias;
        }
    }
}

extern "C" void kernel_launch(void* const* d_in, const int* in_sizes, int n_in,
                              void* d_out, int out_size, void* d_ws, size_t ws_size,
                              hipStream_t stream) {
    const float* X    = (const float*)d_in[0];   // [8192, 4096]
    const float* W    = (const float*)d_in[1];   // [16, 256, 256]
    const float* Bias = (const float*)d_in[2];   // [16, 256]
    float*       Out  = (float*)d_out;           // [8192, 4096]

    dim3 grid(64 * 32);   // 64 M-tiles x 32 N-tiles
    dim3 block(256);
    grouped_linear_kernel<<<grid, block, 0, stream>>>(X, W, Bias, Out);
}